// Round 6
// baseline (1253.226 us; speedup 1.0000x reference)
//
#include <hip/hip_runtime.h>
#include <stdint.h>

using half8  = __attribute__((ext_vector_type(8))) _Float16;
using half4  = __attribute__((ext_vector_type(4))) _Float16;
using f32x4  = __attribute__((ext_vector_type(4))) float;
using f32x16 = __attribute__((ext_vector_type(16))) float;

#define BM 256
#define BN 128
#define BK 32

// Bank-conflict-free layout: granule (row, k8) at byte row*64 + (k8 ^ ((row>>1)&3))*16.
// Read side uses swz(); GLD staging realizes it via pre-swizzled global source
// addresses (LDS dest must be linear: wave-uniform base + lane*16).
__device__ __forceinline__ int swz(int row, int kb) {
  return (row << 6) + ((((kb >> 4) ^ ((row >> 1) & 3)) << 4) | (kb & 15));
}

#define GLD(src, dst)                                                          \
  __builtin_amdgcn_global_load_lds(                                            \
      (const __attribute__((address_space(1))) void*)(src),                    \
      (__attribute__((address_space(3))) void*)(dst), 16, 0, 0)

// Unified tri-buffer counted-vmcnt GEMM, 32x32x16 f16 MFMA (99.8%-of-peak shape).
// C = A*B^T (+bias), split-f16 precision.
// MODE 0: hi/lo inputs -> Chi+Clo.  MODE 1: hi/lo inputs -> Chi only.
// MODE 2: hi-only inputs -> f32 C.
// Schedule: 3 LDS stages, depth-2 GLD prefetch, per-step {vmcnt(counted);
// s_barrier; issue GLDs for ks+2; ds_read; setprio(1) MFMA setprio(0)}.
// No wave ever ds_writes -> single barrier/step + per-wave counted vmcnt
// covers all hazards (3 distinct buffers mod 3).
template <int MODE>
__global__ __launch_bounds__(512, 2)
void gemm_tri(const _Float16* __restrict__ Ahi, const _Float16* __restrict__ Alo,
              const _Float16* __restrict__ Bhi, const _Float16* __restrict__ Blo,
              const float* __restrict__ bias,
              _Float16* __restrict__ Chi, _Float16* __restrict__ Clo,
              float* __restrict__ Cf, int M, int N, int K) {
  constexpr bool LO = (MODE < 2);
  constexpr int AHI = 0;
  constexpr int ALO = 16384;                 // only if LO
  constexpr int BHI = LO ? 32768 : 16384;
  constexpr int BLO = LO ? 40960 : 0;        // only if LO
  constexpr int STG = LO ? 49152 : 24576;    // bytes per stage
  __shared__ char lds[3 * STG];

  const int tid = threadIdx.x;
  const int m0 = blockIdx.y * BM;
  const int n0 = blockIdx.x * BN;
  const int wave = tid >> 6, lane = tid & 63;
  const int wm = wave >> 1, wn = wave & 1;   // 4x2 wave grid; each wave owns 64x64
  const int NK = K / BK;

  f32x16 acc_hi[2][2], acc_mid[2][2];
#pragma unroll
  for (int m = 0; m < 2; m++)
#pragma unroll
    for (int n = 0; n < 2; n++) { acc_hi[m][n] = (f32x16)0.0f; acc_mid[m][n] = (f32x16)0.0f; }

  // Pre-swizzled global source: granule tid: srow = tid>>2 (0..127), slot = tid&3,
  // source k8 = slot ^ ((srow>>1)&3) so linear LDS placement == swizzled layout.
  const int srow = tid >> 2;
  const int kx = (tid & 3) ^ ((srow >> 1) & 3);
  const size_t aoff0 = (size_t)(m0 + srow) * K + kx * 8;
  const size_t aoff1 = aoff0 + (size_t)128 * K;
  const size_t boff  = (size_t)(n0 + srow) * K + kx * 8;

  auto STAGE = [&](int buf, int ks) {
    char* sb = lds + buf * STG + (wave << 10);   // wave-uniform LDS base
    const size_t ko = (size_t)ks * BK;
    GLD(Ahi + aoff0 + ko, sb + AHI);
    GLD(Ahi + aoff1 + ko, sb + AHI + 8192);
    GLD(Bhi + boff + ko, sb + BHI);
    if constexpr (LO) {
      GLD(Alo + aoff0 + ko, sb + ALO);
      GLD(Alo + aoff1 + ko, sb + ALO + 8192);
      GLD(Blo + boff + ko, sb + BLO);
    }
  };

  // 32x32x16 fragments: A row = lane&31, k = (lane>>5)*8 + e (16B granule).
  auto COMPUTE = [&](int buf) {
    char* base = lds + buf * STG;
    const int rl = lane & 31;
    const int kh = (lane >> 5) << 4;   // byte offset of this half-wave's k-chunk
    half8 ah[2][2], al[2][2], bh[2][2], bl[2][2];
#pragma unroll
    for (int mi = 0; mi < 2; mi++)
#pragma unroll
      for (int kk = 0; kk < 2; kk++) {
        int off = swz(wm * 64 + mi * 32 + rl, kk * 32 + kh);
        ah[mi][kk] = *(half8*)(base + AHI + off);
        if constexpr (LO) al[mi][kk] = *(half8*)(base + ALO + off);
      }
#pragma unroll
    for (int ni = 0; ni < 2; ni++)
#pragma unroll
      for (int kk = 0; kk < 2; kk++) {
        int off = swz(wn * 64 + ni * 32 + rl, kk * 32 + kh);
        bh[ni][kk] = *(half8*)(base + BHI + off);
        if constexpr (LO) bl[ni][kk] = *(half8*)(base + BLO + off);
      }
    __builtin_amdgcn_s_setprio(1);
#pragma unroll
    for (int kk = 0; kk < 2; kk++) {
#pragma unroll
      for (int mi = 0; mi < 2; mi++)
#pragma unroll
        for (int ni = 0; ni < 2; ni++)
          acc_hi[mi][ni] = __builtin_amdgcn_mfma_f32_32x32x16_f16(
              ah[mi][kk], bh[ni][kk], acc_hi[mi][ni], 0, 0, 0);
      if constexpr (LO) {
#pragma unroll
        for (int mi = 0; mi < 2; mi++)
#pragma unroll
          for (int ni = 0; ni < 2; ni++)
            acc_mid[mi][ni] = __builtin_amdgcn_mfma_f32_32x32x16_f16(
                ah[mi][kk], bl[ni][kk], acc_mid[mi][ni], 0, 0, 0);
#pragma unroll
        for (int mi = 0; mi < 2; mi++)
#pragma unroll
          for (int ni = 0; ni < 2; ni++)
            acc_mid[mi][ni] = __builtin_amdgcn_mfma_f32_32x32x16_f16(
                al[mi][kk], bh[ni][kk], acc_mid[mi][ni], 0, 0, 0);
      }
    }
    __builtin_amdgcn_s_setprio(0);
  };

  STAGE(0, 0);
  STAGE(1, 1);
  int cur = 0;
  for (int ks = 0; ks < NK; ++ks) {
    if (ks + 1 < NK) {
      if constexpr (LO) asm volatile("s_waitcnt vmcnt(6)" ::: "memory");
      else              asm volatile("s_waitcnt vmcnt(3)" ::: "memory");
    } else {
      asm volatile("s_waitcnt vmcnt(0)" ::: "memory");
    }
    __builtin_amdgcn_s_barrier();
    if (ks + 2 < NK) {
      int nbuf = cur + 2; if (nbuf >= 3) nbuf -= 3;
      STAGE(nbuf, ks + 2);
    }
    COMPUTE(cur);
    if (++cur == 3) cur = 0;
  }

  // Epilogue. 32x32 D-frag: col = lane&31, row = (reg&3) + 8*(reg>>2) + 4*(lane>>5).
  const int col_l = lane & 31;
  const int rbase = (lane >> 5) * 4;
#pragma unroll
  for (int ni = 0; ni < 2; ni++) {
    int col = n0 + wn * 64 + ni * 32 + col_l;
    float bv = bias[col];
#pragma unroll
    for (int mi = 0; mi < 2; mi++) {
      int rowt = m0 + wm * 64 + mi * 32 + rbase;
#pragma unroll
      for (int r = 0; r < 16; r++) {
        int row = rowt + (r & 3) + 8 * (r >> 2);
        size_t idx = (size_t)row * N + col;
        if constexpr (MODE == 2) {
          Cf[idx] = acc_hi[mi][ni][r] + bv;
        } else {
          float c = acc_hi[mi][ni][r] + acc_mid[mi][ni][r] * (1.0f / 2048.0f) + bv;
          _Float16 hh = (_Float16)c;
          Chi[idx] = hh;
          if constexpr (MODE == 0) Clo[idx] = (_Float16)((c - (float)hh) * 2048.0f);
        }
      }
    }
  }
}

// Split f32 -> (hi f16, lo f16 scaled by 2048). Xlo may be null (hi-only).
__global__ __launch_bounds__(256)
void split_kernel(const float* __restrict__ X, _Float16* __restrict__ Xhi,
                  _Float16* __restrict__ Xlo, size_t n4) {
  size_t i = (size_t)blockIdx.x * 256 + threadIdx.x;
  const size_t stride = (size_t)gridDim.x * 256;
  for (; i < n4; i += stride) {
    float4 q = ((const float4*)X)[i];
    float a[4] = {q.x, q.y, q.z, q.w};
    half4 h, l;
#pragma unroll
    for (int j = 0; j < 4; ++j) {
      _Float16 hh = (_Float16)a[j];
      h[j] = hh;
      l[j] = (_Float16)((a[j] - (float)hh) * 2048.0f);
    }
    ((half4*)Xhi)[i] = h;
    if (Xlo) ((half4*)Xlo)[i] = l;
  }
}

// One block per row of Z (hi/lo f16 repr; Zlo may be null):
//  1) reconstruct row; flag |z| < TAU; recompute flagged cols in fp64 from the
//     f32 activation path (Af) or reconstructed hi/lo activations (true sign)
//  2) first all-pos / all-neg group on corrected values
//  3) write back changed elements (group scale/zero + borderline patches)
__global__ __launch_bounds__(256)
void sda_fix(_Float16* __restrict__ Zhi, _Float16* __restrict__ Zlo,
             const float* __restrict__ Af,
             const _Float16* __restrict__ Ahi, const _Float16* __restrict__ Alo,
             const float* __restrict__ W, const float* __restrict__ bias,
             int H, int K) {
  __shared__ int sPos[4], sNeg[4];
  __shared__ int nFix;
  __shared__ int fixIdx[64];
  __shared__ double sRed[4];
  __shared__ float sVal;
  const int row = blockIdx.x;
  _Float16* zh = Zhi + (size_t)row * H;
  _Float16* zl = Zlo ? Zlo + (size_t)row * H : nullptr;
  const int t = threadIdx.x;
  const float TAU = 1e-4f;

  if (t == 0) nFix = 0;
  __syncthreads();

  float v[16];
  {
    half8 a0 = ((const half8*)zh)[t * 2], a1 = ((const half8*)zh)[t * 2 + 1];
    if (zl) {
      half8 b0 = ((const half8*)zl)[t * 2], b1 = ((const half8*)zl)[t * 2 + 1];
#pragma unroll
      for (int e = 0; e < 8; ++e) {
        v[e]     = (float)a0[e] + (float)b0[e] * (1.0f / 2048.0f);
        v[8 + e] = (float)a1[e] + (float)b1[e] * (1.0f / 2048.0f);
      }
    } else {
#pragma unroll
      for (int e = 0; e < 8; ++e) { v[e] = (float)a0[e]; v[8 + e] = (float)a1[e]; }
    }
  }
#pragma unroll
  for (int e = 0; e < 16; ++e) {
    if (fabsf(v[e]) < TAU) {
      int slot = atomicAdd(&nFix, 1);
      if (slot < 64) fixIdx[slot] = (t << 4) + e;
    }
  }
  __syncthreads();
  const int nf = min(nFix, 64);
  unsigned fixmask = 0;
  for (int i = 0; i < nf; ++i) {
    const int col = fixIdx[i];
    double s = 0.0;
    const float* wr = W + (size_t)col * K;
    if (Af) {
      const float* ar = Af + (size_t)row * K;
      for (int k = t; k < K; k += 256) s += (double)ar[k] * (double)wr[k];
    } else {
      const _Float16* ah = Ahi + (size_t)row * K;
      const _Float16* al = Alo + (size_t)row * K;
      for (int k = t; k < K; k += 256)
        s += ((double)(float)ah[k] + (double)(float)al[k] * (1.0 / 2048.0)) * (double)wr[k];
    }
#pragma unroll
    for (int off = 32; off; off >>= 1) s += __shfl_xor(s, off);
    if ((t & 63) == 0) sRed[t >> 6] = s;
    __syncthreads();
    if (t == 0)
      sVal = (float)(sRed[0] + sRed[1] + sRed[2] + sRed[3] + (double)bias[col]);
    __syncthreads();
    if ((col >> 4) == t) { v[col & 15] = sVal; fixmask |= 1u << (col & 15); }
  }
  __syncthreads();

  int fp = 0x7fffffff, fn = 0x7fffffff;
#pragma unroll
  for (int j = 0; j < 4; ++j) {
    bool ap = (v[j*4+0] > 0.f) & (v[j*4+1] > 0.f) & (v[j*4+2] > 0.f) & (v[j*4+3] > 0.f);
    bool an = (v[j*4+0] < 0.f) & (v[j*4+1] < 0.f) & (v[j*4+2] < 0.f) & (v[j*4+3] < 0.f);
    int g = (t << 2) + j;
    if (ap && g < fp) fp = g;
    if (an && g < fn) fn = g;
  }
#pragma unroll
  for (int off = 32; off; off >>= 1) {
    fp = min(fp, __shfl_xor(fp, off));
    fn = min(fn, __shfl_xor(fn, off));
  }
  if ((t & 63) == 0) { sPos[t >> 6] = fp; sNeg[t >> 6] = fn; }
  __syncthreads();
  fp = min(min(sPos[0], sPos[1]), min(sPos[2], sPos[3]));
  fn = min(min(sNeg[0], sNeg[1]), min(sNeg[2], sNeg[3]));
  const int act   = (fp == 0x7fffffff) ? -1 : fp;
  const int inact = (fn == 0x7fffffff) ? -1 : fn;

  unsigned chg = fixmask;
#pragma unroll
  for (int j = 0; j < 4; ++j) {
    int g = (t << 2) + j;
    if (g == act) {
      v[j*4+0] *= 2.f; v[j*4+1] *= 2.f; v[j*4+2] *= 2.f; v[j*4+3] *= 2.f;
      chg |= 0xFu << (j * 4);
    } else if (g == inact) {
      v[j*4+0] = v[j*4+1] = v[j*4+2] = v[j*4+3] = 0.f;
      chg |= 0xFu << (j * 4);
    }
  }
  while (chg) {
    int e = __ffs(chg) - 1; chg &= chg - 1;
    float val = v[e];
    _Float16 hh = (_Float16)val;
    zh[(t << 4) + e] = hh;
    if (zl) zl[(t << 4) + e] = (_Float16)((val - (float)hh) * 2048.0f);
  }
}

extern "C" void kernel_launch(void* const* d_in, const int* in_sizes, int n_in,
                              void* d_out, int out_size, void* d_ws, size_t ws_size,
                              hipStream_t stream) {
  const float* x  = (const float*)d_in[0];
  const float* W1 = (const float*)d_in[1];
  const float* b1 = (const float*)d_in[2];
  const float* W2 = (const float*)d_in[3];
  const float* b2 = (const float*)d_in[4];
  const float* W3 = (const float*)d_in[5];
  const float* b3 = (const float*)d_in[6];
  float* out = (float*)d_out;

  const int M = 8192, H = 4096, DIN = 1024, DOUT = 1024;

  // Scratch: 256 MiB total, with time-sliced aliasing.
  //   @0   Z1hi 64MB
  //   @64  Z1lo 64MB              (dead after sda_fix(L2); W3hi reuses @64)
  //   @128 Z2hi 64MB — before L2, aliased as xhi(16) xlo(16) W1hi(8) W1lo(8)
  //   @192 W2hi 32MB
  //   @224 W2lo 32MB
  char* w = (char*)d_ws;
  _Float16* Z1hi = (_Float16*)(w + 0);
  _Float16* Z1lo = (_Float16*)(w + ((size_t)64 << 20));
  _Float16* Z2hi = (_Float16*)(w + ((size_t)128 << 20));
  _Float16* W2hi = (_Float16*)(w + ((size_t)192 << 20));
  _Float16* W2lo = (_Float16*)(w + ((size_t)224 << 20));
  // aliases (dead before their region's long-term owner is written)
  _Float16* xhi  = (_Float16*)(w + ((size_t)128 << 20));
  _Float16* xlo  = (_Float16*)(w + ((size_t)144 << 20));
  _Float16* W1hi = (_Float16*)(w + ((size_t)160 << 20));
  _Float16* W1lo = (_Float16*)(w + ((size_t)168 << 20));
  _Float16* W3hi = (_Float16*)(w + ((size_t)64 << 20));   // after sda_fix(L2)

  auto split = [&](const float* src, _Float16* hi, _Float16* lo, size_t n) {
    size_t n4 = n >> 2;
    int grid = (int)((n4 + 255) / 256);
    if (grid > 2048) grid = 2048;
    split_kernel<<<grid, 256, 0, stream>>>(src, hi, lo, n4);
  };
  split(x,  xhi,  xlo,  (size_t)M * DIN);
  split(W1, W1hi, W1lo, (size_t)H * DIN);
  split(W2, W2hi, W2lo, (size_t)H * H);

  dim3 blk(512);
  // L1: Z1 = x @ W1^T + b1   (K=1024) — presplit in, hi/lo out
  gemm_tri<0><<<dim3(H / BN, M / BM), blk, 0, stream>>>(
      xhi, xlo, W1hi, W1lo, b1, Z1hi, Z1lo, (float*)nullptr, M, H, DIN);
  sda_fix<<<M, 256, 0, stream>>>(Z1hi, Z1lo, x, (const _Float16*)nullptr,
                                 (const _Float16*)nullptr, W1, b1, H, DIN);
  // L2: Z2 = Z1 @ W2^T + b2  (K=4096) — presplit in, hi out (overwrites x/W1 splits)
  gemm_tri<1><<<dim3(H / BN, M / BM), blk, 0, stream>>>(
      Z1hi, Z1lo, W2hi, W2lo, b2, Z2hi, (_Float16*)nullptr, (float*)nullptr, M, H, H);
  sda_fix<<<M, 256, 0, stream>>>(Z2hi, (_Float16*)nullptr, (const float*)nullptr,
                                 Z1hi, Z1lo, W2, b2, H, H);
  // L3: out = Z2 @ W3^T + b3 (N=1024) — hi-only (W3hi reuses dead Z1lo region)
  split(W3, W3hi, (_Float16*)nullptr, (size_t)DOUT * H);
  gemm_tri<2><<<dim3(DOUT / BN, M / BM), blk, 0, stream>>>(
      Z2hi, (const _Float16*)nullptr, W3hi, (const _Float16*)nullptr, b3,
      (_Float16*)nullptr, (_Float16*)nullptr, out, M, DOUT, H);
}

// Round 7
// 1091.462 us; speedup vs baseline: 1.1482x; 1.1482x over previous
//
#include <hip/hip_runtime.h>
#include <stdint.h>

using half8 = __attribute__((ext_vector_type(8))) _Float16;
using half4 = __attribute__((ext_vector_type(4))) _Float16;
using f32x4 = __attribute__((ext_vector_type(4))) float;

#define BM 256
#define BN 128
#define BK 32

// Bank-conflict-free layout: granule (row, k8) at byte row*64 + (k8 ^ ((row>>1)&3))*16.
// Read side uses swz() (16-row column reads -> 2-way aliasing = free);
// GLD staging realizes it via pre-swizzled global source addresses
// (LDS dest must be linear: wave-uniform base + lane*16).
__device__ __forceinline__ int swz(int row, int kb) {
  return (row << 6) + ((((kb >> 4) ^ ((row >> 1) & 3)) << 4) | (kb & 15));
}

#define GLD(src, dst)                                                          \
  __builtin_amdgcn_global_load_lds(                                            \
      (const __attribute__((address_space(1))) void*)(src),                    \
      (__attribute__((address_space(3))) void*)(dst), 16, 0, 0)

// Unified tri-buffer counted-vmcnt GEMM, 16x16x32 f16 MFMA, 16 waves (4/SIMD).
// C = A*B^T (+bias), split-f16 precision (3 products: hi*hi, hi*lo, lo*hi).
// MODE 0: hi/lo inputs -> Chi+Clo.  MODE 1: hi/lo inputs -> Chi only.
// MODE 2: hi-only inputs -> f32 C.
// Schedule: 3 LDS stages, depth-2 GLD prefetch, per-step {vmcnt(counted);
// s_barrier; issue GLDs for ks+2; ds_read; setprio(1) MFMA setprio(0)}.
// Hazard proof: no wave ds_writes (all LDS writes via GLD). Each wave's
// vmcnt(N) BEFORE the barrier confirms its own oldest stage landed; the
// barrier publishes it to readers. GLD targets buf(ks+2) which was last
// read at step ks-1, separated by the barrier. 3 buffers keep pending
// reads (ks), in-flight writes (ks+1), and new writes (ks+2) disjoint.
template <int MODE>
__global__ __launch_bounds__(1024, 4)
void gemm_tri(const _Float16* __restrict__ Ahi, const _Float16* __restrict__ Alo,
              const _Float16* __restrict__ Bhi, const _Float16* __restrict__ Blo,
              const float* __restrict__ bias,
              _Float16* __restrict__ Chi, _Float16* __restrict__ Clo,
              float* __restrict__ Cf, int M, int N, int K) {
  constexpr bool LO = (MODE < 2);
  constexpr int AHI = 0;
  constexpr int ALO = 16384;                 // only if LO
  constexpr int BHI = LO ? 32768 : 16384;
  constexpr int BLO = 40960;                 // only if LO
  constexpr int STG = LO ? 49152 : 24576;    // bytes per stage
  __shared__ char lds[3 * STG];

  const int tid = threadIdx.x;
  const int m0 = blockIdx.y * BM;
  const int n0 = blockIdx.x * BN;
  const int wave = tid >> 6, lane = tid & 63;
  const int wm = wave >> 1, wn = wave & 1;   // 8x2 wave grid; wave tile 32x64
  const int NK = K / BK;

  f32x4 acc_hi[2][4], acc_mid[2][4];
#pragma unroll
  for (int m = 0; m < 2; m++)
#pragma unroll
    for (int n = 0; n < 4; n++) { acc_hi[m][n] = (f32x4)0.0f; acc_mid[m][n] = (f32x4)0.0f; }

  // Pre-swizzled source: thread tid stages granule (row=tid>>2, k8=(tid&3)^swz)
  // into linear LDS slot tid*16, so linear placement == swizzled layout.
  const int srow = tid >> 2;                  // 0..255 (A rows)
  const int kx = (tid & 3) ^ ((srow >> 1) & 3);
  const size_t aoff = (size_t)(m0 + srow) * K + kx * 8;
  const int brow = (tid & 511) >> 2;          // 0..127 (B rows); same bits 1-2 -> same kx
  const size_t boff = (size_t)(n0 + brow) * K + kx * 8;

  // A: every wave stages its 1KB slice of Ahi (and Alo). B: waves 0-7 stage
  // Bhi, waves 8-15 stage Blo (MODE2: only Bhi, waves 0-7).
  auto STAGE = [&](int buf, int ks) {
    char* sb = lds + buf * STG;
    const size_t ko = (size_t)ks * BK;
    GLD(Ahi + aoff + ko, sb + AHI + (wave << 10));
    if constexpr (LO) {
      GLD(Alo + aoff + ko, sb + ALO + (wave << 10));
      if (wave < 8) GLD(Bhi + boff + ko, sb + BHI + (wave << 10));
      else          GLD(Blo + boff + ko, sb + BLO + ((wave - 8) << 10));
    } else {
      if (wave < 8) GLD(Bhi + boff + ko, sb + BHI + (wave << 10));
    }
  };

  auto COMPUTE = [&](int buf) {
    char* base = lds + buf * STG;
    const int kb = (lane >> 4) << 4;
    const int rl = lane & 15;
    half8 ah[2], al[2], bh[4], bl[4];
#pragma unroll
    for (int mi = 0; mi < 2; mi++) {
      int off = swz(wm * 32 + mi * 16 + rl, kb);
      ah[mi] = *(half8*)(base + AHI + off);
      if constexpr (LO) al[mi] = *(half8*)(base + ALO + off);
    }
#pragma unroll
    for (int ni = 0; ni < 4; ni++) {
      int off = swz(wn * 64 + ni * 16 + rl, kb);
      bh[ni] = *(half8*)(base + BHI + off);
      if constexpr (LO) bl[ni] = *(half8*)(base + BLO + off);
    }
    __builtin_amdgcn_s_setprio(1);
#pragma unroll
    for (int mi = 0; mi < 2; mi++)
#pragma unroll
      for (int ni = 0; ni < 4; ni++) {
        acc_hi[mi][ni] = __builtin_amdgcn_mfma_f32_16x16x32_f16(ah[mi], bh[ni], acc_hi[mi][ni], 0, 0, 0);
        if constexpr (LO) {
          acc_mid[mi][ni] = __builtin_amdgcn_mfma_f32_16x16x32_f16(ah[mi], bl[ni], acc_mid[mi][ni], 0, 0, 0);
          acc_mid[mi][ni] = __builtin_amdgcn_mfma_f32_16x16x32_f16(al[mi], bh[ni], acc_mid[mi][ni], 0, 0, 0);
        }
      }
    __builtin_amdgcn_s_setprio(0);
  };

  STAGE(0, 0);
  STAGE(1, 1);
  int cur = 0;
  for (int ks = 0; ks < NK; ++ks) {
    if (ks + 1 < NK) {
      if constexpr (LO) {
        asm volatile("s_waitcnt vmcnt(3)" ::: "memory");
      } else {
        if (wave < 8) asm volatile("s_waitcnt vmcnt(2)" ::: "memory");
        else          asm volatile("s_waitcnt vmcnt(1)" ::: "memory");
      }
    } else {
      asm volatile("s_waitcnt vmcnt(0)" ::: "memory");
    }
    __builtin_amdgcn_s_barrier();
    if (ks + 2 < NK) {
      int nbuf = cur + 2; if (nbuf >= 3) nbuf -= 3;
      STAGE(nbuf, ks + 2);
    }
    COMPUTE(cur);
    if (++cur == 3) cur = 0;
  }

  // Epilogue. D-frag: col=lane&15, row=(lane>>4)*4+i.
  const int col_l = lane & 15, rgrp = lane >> 4;
#pragma unroll
  for (int ni = 0; ni < 4; ni++) {
    int col = n0 + wn * 64 + ni * 16 + col_l;
    float bv = bias[col];
#pragma unroll
    for (int mi = 0; mi < 2; mi++) {
      int rowb = m0 + wm * 32 + mi * 16 + rgrp * 4;
#pragma unroll
      for (int i = 0; i < 4; i++) {
        size_t idx = (size_t)(rowb + i) * N + col;
        if constexpr (MODE == 2) {
          Cf[idx] = acc_hi[mi][ni][i] + bv;
        } else {
          float c = acc_hi[mi][ni][i] + acc_mid[mi][ni][i] * (1.0f / 2048.0f) + bv;
          _Float16 hh = (_Float16)c;
          Chi[idx] = hh;
          if constexpr (MODE == 0) Clo[idx] = (_Float16)((c - (float)hh) * 2048.0f);
        }
      }
    }
  }
}

// Split f32 -> (hi f16, lo f16 scaled by 2048). Xlo may be null (hi-only).
__global__ __launch_bounds__(256)
void split_kernel(const float* __restrict__ X, _Float16* __restrict__ Xhi,
                  _Float16* __restrict__ Xlo, size_t n4) {
  size_t i = (size_t)blockIdx.x * 256 + threadIdx.x;
  const size_t stride = (size_t)gridDim.x * 256;
  for (; i < n4; i += stride) {
    float4 q = ((const float4*)X)[i];
    float a[4] = {q.x, q.y, q.z, q.w};
    half4 h, l;
#pragma unroll
    for (int j = 0; j < 4; ++j) {
      _Float16 hh = (_Float16)a[j];
      h[j] = hh;
      l[j] = (_Float16)((a[j] - (float)hh) * 2048.0f);
    }
    ((half4*)Xhi)[i] = h;
    if (Xlo) ((half4*)Xlo)[i] = l;
  }
}

// One block per row of Z (hi/lo f16 repr; Zlo may be null):
//  1) reconstruct row; flag |z| < TAU; recompute flagged cols in fp64 from the
//     f32 activation path (Af) or reconstructed hi/lo activations (true sign)
//  2) first all-pos / all-neg group on corrected values
//  3) write back changed elements (group scale/zero + borderline patches)
__global__ __launch_bounds__(256)
void sda_fix(_Float16* __restrict__ Zhi, _Float16* __restrict__ Zlo,
             const float* __restrict__ Af,
             const _Float16* __restrict__ Ahi, const _Float16* __restrict__ Alo,
             const float* __restrict__ W, const float* __restrict__ bias,
             int H, int K) {
  __shared__ int sPos[4], sNeg[4];
  __shared__ int nFix;
  __shared__ int fixIdx[64];
  __shared__ double sRed[4];
  __shared__ float sVal;
  const int row = blockIdx.x;
  _Float16* zh = Zhi + (size_t)row * H;
  _Float16* zl = Zlo ? Zlo + (size_t)row * H : nullptr;
  const int t = threadIdx.x;
  const float TAU = 1e-4f;

  if (t == 0) nFix = 0;
  __syncthreads();

  float v[16];
  {
    half8 a0 = ((const half8*)zh)[t * 2], a1 = ((const half8*)zh)[t * 2 + 1];
    if (zl) {
      half8 b0 = ((const half8*)zl)[t * 2], b1 = ((const half8*)zl)[t * 2 + 1];
#pragma unroll
      for (int e = 0; e < 8; ++e) {
        v[e]     = (float)a0[e] + (float)b0[e] * (1.0f / 2048.0f);
        v[8 + e] = (float)a1[e] + (float)b1[e] * (1.0f / 2048.0f);
      }
    } else {
#pragma unroll
      for (int e = 0; e < 8; ++e) { v[e] = (float)a0[e]; v[8 + e] = (float)a1[e]; }
    }
  }
#pragma unroll
  for (int e = 0; e < 16; ++e) {
    if (fabsf(v[e]) < TAU) {
      int slot = atomicAdd(&nFix, 1);
      if (slot < 64) fixIdx[slot] = (t << 4) + e;
    }
  }
  __syncthreads();
  const int nf = min(nFix, 64);
  unsigned fixmask = 0;
  for (int i = 0; i < nf; ++i) {
    const int col = fixIdx[i];
    double s = 0.0;
    const float* wr = W + (size_t)col * K;
    if (Af) {
      const float* ar = Af + (size_t)row * K;
      for (int k = t; k < K; k += 256) s += (double)ar[k] * (double)wr[k];
    } else {
      const _Float16* ah = Ahi + (size_t)row * K;
      const _Float16* al = Alo + (size_t)row * K;
      for (int k = t; k < K; k += 256)
        s += ((double)(float)ah[k] + (double)(float)al[k] * (1.0 / 2048.0)) * (double)wr[k];
    }
#pragma unroll
    for (int off = 32; off; off >>= 1) s += __shfl_xor(s, off);
    if ((t & 63) == 0) sRed[t >> 6] = s;
    __syncthreads();
    if (t == 0)
      sVal = (float)(sRed[0] + sRed[1] + sRed[2] + sRed[3] + (double)bias[col]);
    __syncthreads();
    if ((col >> 4) == t) { v[col & 15] = sVal; fixmask |= 1u << (col & 15); }
  }
  __syncthreads();

  int fp = 0x7fffffff, fn = 0x7fffffff;
#pragma unroll
  for (int j = 0; j < 4; ++j) {
    bool ap = (v[j*4+0] > 0.f) & (v[j*4+1] > 0.f) & (v[j*4+2] > 0.f) & (v[j*4+3] > 0.f);
    bool an = (v[j*4+0] < 0.f) & (v[j*4+1] < 0.f) & (v[j*4+2] < 0.f) & (v[j*4+3] < 0.f);
    int g = (t << 2) + j;
    if (ap && g < fp) fp = g;
    if (an && g < fn) fn = g;
  }
#pragma unroll
  for (int off = 32; off; off >>= 1) {
    fp = min(fp, __shfl_xor(fp, off));
    fn = min(fn, __shfl_xor(fn, off));
  }
  if ((t & 63) == 0) { sPos[t >> 6] = fp; sNeg[t >> 6] = fn; }
  __syncthreads();
  fp = min(min(sPos[0], sPos[1]), min(sPos[2], sPos[3]));
  fn = min(min(sNeg[0], sNeg[1]), min(sNeg[2], sNeg[3]));
  const int act   = (fp == 0x7fffffff) ? -1 : fp;
  const int inact = (fn == 0x7fffffff) ? -1 : fn;

  unsigned chg = fixmask;
#pragma unroll
  for (int j = 0; j < 4; ++j) {
    int g = (t << 2) + j;
    if (g == act) {
      v[j*4+0] *= 2.f; v[j*4+1] *= 2.f; v[j*4+2] *= 2.f; v[j*4+3] *= 2.f;
      chg |= 0xFu << (j * 4);
    } else if (g == inact) {
      v[j*4+0] = v[j*4+1] = v[j*4+2] = v[j*4+3] = 0.f;
      chg |= 0xFu << (j * 4);
    }
  }
  while (chg) {
    int e = __ffs(chg) - 1; chg &= chg - 1;
    float val = v[e];
    _Float16 hh = (_Float16)val;
    zh[(t << 4) + e] = hh;
    if (zl) zl[(t << 4) + e] = (_Float16)((val - (float)hh) * 2048.0f);
  }
}

extern "C" void kernel_launch(void* const* d_in, const int* in_sizes, int n_in,
                              void* d_out, int out_size, void* d_ws, size_t ws_size,
                              hipStream_t stream) {
  const float* x  = (const float*)d_in[0];
  const float* W1 = (const float*)d_in[1];
  const float* b1 = (const float*)d_in[2];
  const float* W2 = (const float*)d_in[3];
  const float* b2 = (const float*)d_in[4];
  const float* W3 = (const float*)d_in[5];
  const float* b3 = (const float*)d_in[6];
  float* out = (float*)d_out;

  const int M = 8192, H = 4096, DIN = 1024, DOUT = 1024;

  // Scratch: 256 MiB total, with time-sliced aliasing.
  //   @0   Z1hi 64MB
  //   @64  Z1lo 64MB              (dead after sda_fix(L2); W3hi reuses @64)
  //   @128 Z2hi 64MB — before L2, aliased as xhi(16) xlo(16) W1hi(8) W1lo(8)
  //   @192 W2hi 32MB
  //   @224 W2lo 32MB
  char* w = (char*)d_ws;
  _Float16* Z1hi = (_Float16*)(w + 0);
  _Float16* Z1lo = (_Float16*)(w + ((size_t)64 << 20));
  _Float16* Z2hi = (_Float16*)(w + ((size_t)128 << 20));
  _Float16* W2hi = (_Float16*)(w + ((size_t)192 << 20));
  _Float16* W2lo = (_Float16*)(w + ((size_t)224 << 20));
  // aliases (dead before their region's long-term owner is written)
  _Float16* xhi  = (_Float16*)(w + ((size_t)128 << 20));
  _Float16* xlo  = (_Float16*)(w + ((size_t)144 << 20));
  _Float16* W1hi = (_Float16*)(w + ((size_t)160 << 20));
  _Float16* W1lo = (_Float16*)(w + ((size_t)168 << 20));
  _Float16* W3hi = (_Float16*)(w + ((size_t)64 << 20));   // after sda_fix(L2)

  auto split = [&](const float* src, _Float16* hi, _Float16* lo, size_t n) {
    size_t n4 = n >> 2;
    int grid = (int)((n4 + 255) / 256);
    if (grid > 2048) grid = 2048;
    split_kernel<<<grid, 256, 0, stream>>>(src, hi, lo, n4);
  };
  split(x,  xhi,  xlo,  (size_t)M * DIN);
  split(W1, W1hi, W1lo, (size_t)H * DIN);
  split(W2, W2hi, W2lo, (size_t)H * H);

  dim3 blk(1024);
  // L1: Z1 = x @ W1^T + b1   (K=1024) — presplit in, hi/lo out
  gemm_tri<0><<<dim3(H / BN, M / BM), blk, 0, stream>>>(
      xhi, xlo, W1hi, W1lo, b1, Z1hi, Z1lo, (float*)nullptr, M, H, DIN);
  sda_fix<<<M, 256, 0, stream>>>(Z1hi, Z1lo, x, (const _Float16*)nullptr,
                                 (const _Float16*)nullptr, W1, b1, H, DIN);
  // L2: Z2 = Z1 @ W2^T + b2  (K=4096) — presplit in, hi out (overwrites x/W1 splits)
  gemm_tri<1><<<dim3(H / BN, M / BM), blk, 0, stream>>>(
      Z1hi, Z1lo, W2hi, W2lo, b2, Z2hi, (_Float16*)nullptr, (float*)nullptr, M, H, H);
  sda_fix<<<M, 256, 0, stream>>>(Z2hi, (_Float16*)nullptr, (const float*)nullptr,
                                 Z1hi, Z1lo, W2, b2, H, H);
  // L3: out = Z2 @ W3^T + b3 (N=1024) — hi-only (W3hi reuses dead Z1lo region)
  split(W3, W3hi, (_Float16*)nullptr, (size_t)DOUT * H);
  gemm_tri<2><<<dim3(DOUT / BN, M / BM), blk, 0, stream>>>(
      Z2hi, (const _Float16*)nullptr, W3hi, (const _Float16*)nullptr, b3,
      (_Float16*)nullptr, (_Float16*)nullptr, out, M, DOUT, H);
}